// Round 7
// baseline (222.529 us; speedup 1.0000x reference)
//
#include <hip/hip_runtime.h>

constexpr int Bc = 8, Hc = 16, Sc = 4096, Dc = 64;
constexpr int BH = Bc * Hc;               // 128
constexpr int SS = 8;                     // s-split chunks in k1
constexpr int CHUNK = Sc / SS;            // 512 rows per block
constexpr int WROWS = CHUNK / 4;          // 128 rows per wave
constexpr int MM = Dc * Dc;               // 4096 floats of M per (bh)
constexpr int NZP = SS * 4;               // 32 z partials (per-wave)
constexpr int QT = 128;                   // q-rows per block in k3

// ---- Kernel 1: barrier-free register-streaming outer product ----
// Each wave streams 128 rows; lanes sharing d0/e0 dedup k/v global reads to
// 2x256B coalesced segments per row. No LDS staging, no per-stage barriers.
__global__ __launch_bounds__(256) void k1_accum(const float* __restrict__ K,
                                                const float* __restrict__ V,
                                                float* __restrict__ Pm,
                                                double* __restrict__ Pz) {
  const int blk = blockIdx.x;
  const int bh = blk >> 3;       // 0..127
  const int ck = blk & 7;        // 0..7
  const int tid = threadIdx.x;
  const int w = tid >> 6;        // wave 0..3: rows [w*128, w*128+128)
  const int l = tid & 63;
  const int d0 = (l >> 3) * 8;   // k-dim tile base
  const int e0 = (l & 7) * 8;    // v-dim tile base

  const size_t rbase = ((size_t)bh * Sc + (size_t)ck * CHUNK + (size_t)w * WROWS) * Dc;
  const float* kp = K + rbase;
  const float* vp = V + rbase;

  float acc[8][8] = {};
  double zacc = 0.0;

  float4 ka0, kb0, va0, vb0; float z0;
  float4 ka1, kb1, va1, vb1; float z1;

#define K1_LOAD(S, r)                                                  \
  ka##S = *(const float4*)(kp + (size_t)(r) * 64 + d0);                \
  kb##S = *(const float4*)(kp + (size_t)(r) * 64 + d0 + 4);            \
  va##S = *(const float4*)(vp + (size_t)(r) * 64 + e0);                \
  vb##S = *(const float4*)(vp + (size_t)(r) * 64 + e0 + 4);            \
  z##S = kp[(size_t)(r) * 64 + l];

#define K1_COMP(S)                                                     \
  {                                                                    \
    const float kk[8] = {ka##S.x, ka##S.y, ka##S.z, ka##S.w,           \
                         kb##S.x, kb##S.y, kb##S.z, kb##S.w};          \
    const float vv[8] = {va##S.x, va##S.y, va##S.z, va##S.w,           \
                         vb##S.x, vb##S.y, vb##S.z, vb##S.w};          \
    _Pragma("unroll")                                                  \
    for (int a = 0; a < 8; ++a)                                        \
      _Pragma("unroll")                                                \
      for (int b = 0; b < 8; ++b)                                      \
        acc[a][b] = fmaf(kk[a], vv[b], acc[a][b]);                     \
    zacc += (double)z##S;                                              \
  }

  // depth-2 software pipeline over rows (no barriers -> loads stay in flight)
  K1_LOAD(0, 0)
  K1_LOAD(1, 1)
  for (int r = 0; r < WROWS - 2; r += 2) {
    K1_COMP(0)
    K1_LOAD(0, r + 2)
    K1_COMP(1)
    K1_LOAD(1, r + 3)
  }
  K1_COMP(0)
  K1_COMP(1)
#undef K1_LOAD
#undef K1_COMP

  // combine 4 wave-partials of M in smem: order ((p0+p1)+p2)+p3
  __shared__ __align__(16) float smem[MM];
  #pragma unroll
  for (int p = 0; p < 4; ++p) {
    if (w == p) {
      #pragma unroll
      for (int a = 0; a < 8; ++a) {
        float* dst = &smem[(d0 + a) * 64 + e0];
        float4 lo = make_float4(acc[a][0], acc[a][1], acc[a][2], acc[a][3]);
        float4 hi = make_float4(acc[a][4], acc[a][5], acc[a][6], acc[a][7]);
        if (p == 0) {
          *(float4*)dst = lo; *(float4*)(dst + 4) = hi;
        } else {
          float4 olo = *(float4*)dst, ohi = *(float4*)(dst + 4);
          olo.x += lo.x; olo.y += lo.y; olo.z += lo.z; olo.w += lo.w;
          ohi.x += hi.x; ohi.y += hi.y; ohi.z += hi.z; ohi.w += hi.w;
          *(float4*)dst = olo; *(float4*)(dst + 4) = ohi;
        }
      }
    }
    __syncthreads();
  }

  // coalesced Pm write from smem
  float* pd = Pm + ((size_t)ck * BH + bh) * MM;
  #pragma unroll
  for (int j = 0; j < 4; ++j) {
    const int idx = tid + j * 256;
    ((float4*)pd)[idx] = *(const float4*)&smem[idx * 4];
  }
  Pz[((size_t)(ck * 4 + w) * BH + bh) * Dc + l] = zacc;
}

// ---- Kernel 2: reduce M partials (f32); z = f64 exact sum ROUNDED TO F32 ----
__global__ __launch_bounds__(256) void k2_reduce(const float* __restrict__ Pm,
                                                 const double* __restrict__ Pz,
                                                 float* __restrict__ Fm,
                                                 float* __restrict__ Fz) {
  const int i = blockIdx.x * 256 + threadIdx.x;
  const int nm = BH * MM;
  if (i < nm) {
    float s = 0.f;
    #pragma unroll
    for (int c = 0; c < SS; ++c) s += Pm[(size_t)c * nm + i];
    Fm[i] = s;
  }
  const int nz = BH * Dc;
  if (i < nz) {
    double s = 0.0;
    #pragma unroll
    for (int c = 0; c < NZP; ++c) s += Pz[(size_t)c * nz + i];
    Fz[i] = (float)s;   // f32 intermediate matches np bitwise
  }
}

// ---- Kernel 3: out = (q @ M) / (q . z_f32 + eps); 4 rows x 8 cols per thread ----
__global__ __launch_bounds__(256) void k3_retrieve(const float* __restrict__ Q,
                                                   const float* __restrict__ Fm,
                                                   const float* __restrict__ Fz,
                                                   float* __restrict__ O) {
  const int blk = blockIdx.x;             // BH * (Sc/QT) = 128*32
  const int bh = blk >> 5;
  const int row0 = (blk & 31) * QT;

  __shared__ __align__(16) float lm[Dc][Dc];     // 16 KB
  __shared__ __align__(16) float lq[QT][68];     // padded: row stride 68 floats
  __shared__ __align__(16) float lz[Dc];         // f32 z (the np intermediate)

  const int tid = threadIdx.x;

  // stage M: contiguous 16 KB
  const float4* gm4 = (const float4*)(Fm + (size_t)bh * MM);
  float4* lm4 = (float4*)&lm[0][0];
  #pragma unroll
  for (int j = 0; j < 4; ++j) lm4[tid + j * 256] = gm4[tid + j * 256];
  if (tid < Dc) lz[tid] = Fz[(size_t)bh * Dc + tid];

  // stage q rows (coalesced global, padded LDS rows)
  const float4* gq4 = (const float4*)(Q + ((size_t)bh * Sc + row0) * Dc);
  #pragma unroll
  for (int j = 0; j < 8; ++j) {
    const int i4 = tid + j * 256;
    const float4 v = gq4[i4];
    const int f = i4 * 4;
    *(float4*)&lq[f >> 6][f & 63] = v;
  }
  __syncthreads();

  const int rg = tid >> 3;       // 0..31 -> row quad
  const int cg = tid & 7;        // 0..7  -> 8-col block
  const int r0 = rg * 4;
  const int e0 = cg * 8;

  float acc[4][8] = {};
  double den[4] = {0.0, 0.0, 0.0, 0.0};

  #pragma unroll
  for (int ds = 0; ds < 16; ++ds) {
    const int d0 = ds * 4;
    const float4 z4 = *(const float4*)&lz[d0];
    const float* zf = (const float*)&z4;
    float4 q4[4];
    #pragma unroll
    for (int r = 0; r < 4; ++r) q4[r] = *(const float4*)&lq[r0 + r][d0];
    const float* qf[4] = {(const float*)&q4[0], (const float*)&q4[1],
                          (const float*)&q4[2], (const float*)&q4[3]};
    #pragma unroll
    for (int i = 0; i < 4; ++i) {
      const float4 ma = *(const float4*)&lm[d0 + i][e0];
      const float4 mb = *(const float4*)&lm[d0 + i][e0 + 4];
      const float mf[8] = {ma.x, ma.y, ma.z, ma.w, mb.x, mb.y, mb.z, mb.w};
      const double zd = (double)zf[i];
      #pragma unroll
      for (int r = 0; r < 4; ++r) {
        const float qs = qf[r][i];
        den[r] += (double)qs * zd;
        #pragma unroll
        for (int j = 0; j < 8; ++j)
          acc[r][j] = fmaf(qs, mf[j], acc[r][j]);
      }
    }
  }

  #pragma unroll
  for (int r = 0; r < 4; ++r) {
    const double iv = 1.0 / (den[r] + 1e-6);
    float* go = O + ((size_t)bh * Sc + row0 + r0 + r) * Dc + e0;
    ((float4*)go)[0] = make_float4((float)((double)acc[r][0] * iv),
                                   (float)((double)acc[r][1] * iv),
                                   (float)((double)acc[r][2] * iv),
                                   (float)((double)acc[r][3] * iv));
    ((float4*)go)[1] = make_float4((float)((double)acc[r][4] * iv),
                                   (float)((double)acc[r][5] * iv),
                                   (float)((double)acc[r][6] * iv),
                                   (float)((double)acc[r][7] * iv));
  }
}

extern "C" void kernel_launch(void* const* d_in, const int* in_sizes, int n_in,
                              void* d_out, int out_size, void* d_ws, size_t ws_size,
                              hipStream_t stream) {
  const float* K = (const float*)d_in[0];   // keys    [B,H,S,D]
  const float* V = (const float*)d_in[1];   // values
  const float* Q = (const float*)d_in[2];   // queries
  float* O = (float*)d_out;                 // [B,H,S,D]

  float* Pm = (float*)d_ws;                                  // SS*BH*MM floats  (16.8 MB)
  float* Fm = Pm + (size_t)SS * BH * MM;                     // BH*MM floats     (2.1 MB)
  double* Pz = (double*)(Fm + (size_t)BH * MM);              // NZP*BH*Dc doubles (2.1 MB)
  float* Fz = (float*)(Pz + (size_t)NZP * BH * Dc);          // BH*Dc floats     (32 KB)

  hipLaunchKernelGGL(k1_accum, dim3(BH * SS), dim3(256), 0, stream, K, V, Pm, Pz);
  hipLaunchKernelGGL(k2_reduce, dim3((BH * MM + 255) / 256), dim3(256), 0, stream, Pm, Pz, Fm, Fz);
  hipLaunchKernelGGL(k3_retrieve, dim3(BH * (Sc / QT)), dim3(256), 0, stream, Q, Fm, Fz, O);
}